// Round 1
// baseline (781.487 us; speedup 1.0000x reference)
//
#include <hip/hip_runtime.h>
#include <hip/hip_bf16.h>
#include <math.h>

// TriangleMultiplicativeUpdate (outgoing), B=1 N=512 C_Z=C_H=128, fp32 in/out.
// Pipeline: K1 LN(z)->zn bf16 ; K2 proj (a,b transposed to [c][r], gate [r][c]) ;
// K3 per-channel 512^3 BT-GEMM -> x_t[c][i][j] bf16 ; K4 LN+w_z+gate -> out fp32.

#define N 512
#define C 128
#define NN (N*N)
#define PK 136   // padded LDS stride for K=128 bf16 tiles (2-way bank alias = free)
#define PT 40    // padded LDS stride for K=32 bf16 tiles
#define PX 137   // padded LDS stride for fp32 x-tile transpose

typedef __attribute__((ext_vector_type(8))) short bf16x8;
typedef __attribute__((ext_vector_type(4))) float f32x4;
typedef unsigned short u16;
typedef unsigned int u32;

__device__ __forceinline__ u16 f2bf(float f) {
    u32 u = __builtin_bit_cast(u32, f);
    u = (u + 0x7fffu + ((u >> 16) & 1u)) >> 16;
    return (u16)u;
}
__device__ __forceinline__ float bf2f(u16 h) {
    return __builtin_bit_cast(float, ((u32)h) << 16);
}
__device__ __forceinline__ float sigmoidf(float x) {
    return 1.f / (1.f + __expf(-x));
}

// ---------------- K0: weight fp32 [in][out] -> bf16 transposed [out][in] ----
__global__ __launch_bounds__(256) void k_wt(const float* __restrict__ w,
                                            u16* __restrict__ wt) {
    int idx = blockIdx.x * 256 + threadIdx.x;   // grid 64 -> 16384
    int co = idx >> 7, k = idx & 127;
    wt[idx] = f2bf(w[k * C + co]);
}

// ---------------- K1: LayerNorm(z) -> zn bf16 [r][c] ------------------------
__global__ __launch_bounds__(256) void k_ln_in(const float* __restrict__ z,
                                               const float* __restrict__ g,
                                               const float* __restrict__ b,
                                               u16* __restrict__ zn) {
    int wave = threadIdx.x >> 6, lane = threadIdx.x & 63;
    long row = (long)blockIdx.x * 4 + wave;
    const float2 xv = *(const float2*)(z + row * C + lane * 2);
    float s = xv.x + xv.y, s2 = xv.x * xv.x + xv.y * xv.y;
#pragma unroll
    for (int off = 32; off; off >>= 1) {
        s += __shfl_xor(s, off);
        s2 += __shfl_xor(s2, off);
    }
    float mean = s * (1.f / 128.f);
    float var = s2 * (1.f / 128.f) - mean * mean;
    float rs = rsqrtf(var + 1e-5f);
    int c = lane * 2;
    float y0 = (xv.x - mean) * rs * g[c] + b[c];
    float y1 = (xv.y - mean) * rs * g[c + 1] + b[c + 1];
    u32 out = (u32)f2bf(y0) | ((u32)f2bf(y1) << 16);
    *(u32*)(zn + row * C + c) = out;
}

// ---------------- K2a: a/b projection: mask*sigmoid(zn@wg)*(zn@wp) ----------
// writes transposed bf16 [c][r]
__global__ __launch_bounds__(256) void k_proj_gated(
    const u16* __restrict__ zn, const float* __restrict__ mask,
    const u16* __restrict__ wg, const float* __restrict__ bgb,
    const u16* __restrict__ wp, const float* __restrict__ bpb,
    u16* __restrict__ outT) {
    __shared__ u16 sA[64 * PK];
    __shared__ u16 sT[128 * 72];
    long r0 = (long)blockIdx.x * 64;
    int tid = threadIdx.x;
#pragma unroll
    for (int p = 0; p < 4; ++p) {
        int linear = p * 2048 + tid * 8;
        int row = linear >> 7, k = linear & 127;
        *(uint4*)(&sA[row * PK + k]) = *(const uint4*)(zn + (r0 + row) * C + k);
    }
    __syncthreads();
    int wave = tid >> 6, lane = tid & 63, lo = lane & 15, quad = lane >> 4;
    int msub = wave * 16;
    bf16x8 av[4];
#pragma unroll
    for (int ki = 0; ki < 4; ++ki)
        av[ki] = *(const bf16x8*)(&sA[(msub + lo) * PK + ki * 32 + quad * 8]);
    f32x4 accG[8], accP[8];
#pragma unroll
    for (int nt = 0; nt < 8; ++nt) { accG[nt] = (f32x4)(0.f); accP[nt] = (f32x4)(0.f); }
#pragma unroll
    for (int nt = 0; nt < 8; ++nt) {
#pragma unroll
        for (int ki = 0; ki < 4; ++ki) {
            bf16x8 bg8 = *(const bf16x8*)(wg + (nt * 16 + lo) * C + ki * 32 + quad * 8);
            accG[nt] = __builtin_amdgcn_mfma_f32_16x16x32_bf16(av[ki], bg8, accG[nt], 0, 0, 0);
            bf16x8 bp8 = *(const bf16x8*)(wp + (nt * 16 + lo) * C + ki * 32 + quad * 8);
            accP[nt] = __builtin_amdgcn_mfma_f32_16x16x32_bf16(av[ki], bp8, accP[nt], 0, 0, 0);
        }
    }
    float mrow[4];
#pragma unroll
    for (int r = 0; r < 4; ++r) mrow[r] = mask[r0 + msub + quad * 4 + r];
#pragma unroll
    for (int nt = 0; nt < 8; ++nt) {
        int c = nt * 16 + lo;
        float bgv = bgb[c], bpv = bpb[c];
#pragma unroll
        for (int r = 0; r < 4; ++r) {
            int row = msub + quad * 4 + r;
            float val = mrow[r] * sigmoidf(accG[nt][r] + bgv) * (accP[nt][r] + bpv);
            sT[c * 72 + row] = f2bf(val);
        }
    }
    __syncthreads();
#pragma unroll
    for (int p = 0; p < 4; ++p) {
        int linear = p * 2048 + tid * 8;
        int c = linear >> 6, row = linear & 63;
        *(uint4*)(outT + (long)c * NN + r0 + row) = *(const uint4*)(&sT[c * 72 + row]);
    }
}

// ---------------- K2b: gate = sigmoid(zn@w_g + b_g) bf16 [r][c] -------------
__global__ __launch_bounds__(256) void k_proj_gate(
    const u16* __restrict__ zn,
    const u16* __restrict__ wg, const float* __restrict__ bgb,
    u16* __restrict__ gate) {
    __shared__ u16 sA[64 * PK];
    long r0 = (long)blockIdx.x * 64;
    int tid = threadIdx.x;
#pragma unroll
    for (int p = 0; p < 4; ++p) {
        int linear = p * 2048 + tid * 8;
        int row = linear >> 7, k = linear & 127;
        *(uint4*)(&sA[row * PK + k]) = *(const uint4*)(zn + (r0 + row) * C + k);
    }
    __syncthreads();
    int wave = tid >> 6, lane = tid & 63, lo = lane & 15, quad = lane >> 4;
    int msub = wave * 16;
    bf16x8 av[4];
#pragma unroll
    for (int ki = 0; ki < 4; ++ki)
        av[ki] = *(const bf16x8*)(&sA[(msub + lo) * PK + ki * 32 + quad * 8]);
    f32x4 acc[8];
#pragma unroll
    for (int nt = 0; nt < 8; ++nt) acc[nt] = (f32x4)(0.f);
#pragma unroll
    for (int nt = 0; nt < 8; ++nt)
#pragma unroll
        for (int ki = 0; ki < 4; ++ki) {
            bf16x8 b8 = *(const bf16x8*)(wg + (nt * 16 + lo) * C + ki * 32 + quad * 8);
            acc[nt] = __builtin_amdgcn_mfma_f32_16x16x32_bf16(av[ki], b8, acc[nt], 0, 0, 0);
        }
    __syncthreads();  // done reading sA, reuse as [row][c] staging
#pragma unroll
    for (int nt = 0; nt < 8; ++nt) {
        int c = nt * 16 + lo;
        float bv = bgb[c];
#pragma unroll
        for (int r = 0; r < 4; ++r) {
            int row = msub + quad * 4 + r;
            sA[row * PK + c] = f2bf(sigmoidf(acc[nt][r] + bv));
        }
    }
    __syncthreads();
#pragma unroll
    for (int p = 0; p < 4; ++p) {
        int linear = p * 2048 + tid * 8;
        int row = linear >> 7, k = linear & 127;
        *(uint4*)(gate + (r0 + row) * C + k) = *(const uint4*)(&sA[row * PK + k]);
    }
}

// ---------------- K3: per-channel 512x512x512 BT-GEMM -----------------------
// x_t[c][i][j] = sum_k a_t[c][i][k] * b_t[c][j][k]
__global__ __launch_bounds__(256) void k_tri(const u16* __restrict__ aT,
                                             const u16* __restrict__ bT,
                                             u16* __restrict__ xT) {
    __shared__ u16 sA[128 * PT];
    __shared__ u16 sB[128 * PT];
    int c = blockIdx.y;
    int i0 = (blockIdx.x >> 2) * 128, j0 = (blockIdx.x & 3) * 128;
    const u16* aBase = aT + (long)c * NN + (long)i0 * N;
    const u16* bBase = bT + (long)c * NN + (long)j0 * N;
    int tid = threadIdx.x;
    int wave = tid >> 6, lane = tid & 63, lo = lane & 15, quad = lane >> 4;
    int mq = (wave >> 1) * 64, nq = (wave & 1) * 64;
    f32x4 acc[4][4];
#pragma unroll
    for (int mi = 0; mi < 4; ++mi)
#pragma unroll
        for (int ni = 0; ni < 4; ++ni) acc[mi][ni] = (f32x4)(0.f);
    for (int kk = 0; kk < N; kk += 32) {
        __syncthreads();
#pragma unroll
        for (int p = 0; p < 2; ++p) {
            int linear = p * 2048 + tid * 8;
            int row = linear >> 5, k = linear & 31;
            *(uint4*)(&sA[row * PT + k]) = *(const uint4*)(aBase + row * N + kk + k);
            *(uint4*)(&sB[row * PT + k]) = *(const uint4*)(bBase + row * N + kk + k);
        }
        __syncthreads();
        bf16x8 af[4], bfr[4];
#pragma unroll
        for (int mi = 0; mi < 4; ++mi)
            af[mi] = *(const bf16x8*)(&sA[(mq + mi * 16 + lo) * PT + quad * 8]);
#pragma unroll
        for (int ni = 0; ni < 4; ++ni)
            bfr[ni] = *(const bf16x8*)(&sB[(nq + ni * 16 + lo) * PT + quad * 8]);
#pragma unroll
        for (int mi = 0; mi < 4; ++mi)
#pragma unroll
            for (int ni = 0; ni < 4; ++ni)
                acc[mi][ni] = __builtin_amdgcn_mfma_f32_16x16x32_bf16(af[mi], bfr[ni], acc[mi][ni], 0, 0, 0);
    }
    u16* outBase = xT + (long)c * NN;
#pragma unroll
    for (int mi = 0; mi < 4; ++mi)
#pragma unroll
        for (int ni = 0; ni < 4; ++ni)
#pragma unroll
            for (int r = 0; r < 4; ++r) {
                int gi = i0 + mq + mi * 16 + quad * 4 + r;
                int gj = j0 + nq + ni * 16 + lo;
                outBase[(long)gi * N + gj] = f2bf(acc[mi][ni][r]);
            }
}

// ---------------- K4: LN(x) @ w_z + b_z, * gate -> out fp32 -----------------
__global__ __launch_bounds__(256) void k_out(
    const u16* __restrict__ xT, const u16* __restrict__ gate,
    const u16* __restrict__ wzT, const float* __restrict__ bz,
    const float* __restrict__ lg, const float* __restrict__ lb,
    float* __restrict__ out) {
    __shared__ float sX[64 * PX];
    __shared__ u16 sA[64 * PK];
    __shared__ float sRed[2][4][64];
    __shared__ float2 sMV[64];
    long r0 = (long)blockIdx.x * 64;
    int tid = threadIdx.x;
#pragma unroll
    for (int p = 0; p < 4; ++p) {
        int linear = p * 2048 + tid * 8;
        int cc = linear >> 6, jr = linear & 63;
        uint4 v = *(const uint4*)(xT + (long)cc * NN + r0 + jr);
        u16* u = (u16*)&v;
#pragma unroll
        for (int e = 0; e < 8; ++e) sX[(jr + e) * PX + cc] = bf2f(u[e]);
    }
    __syncthreads();
    {
        int jr = tid & 63, part = tid >> 6;
        float s = 0, s2 = 0;
#pragma unroll
        for (int c = part * 32; c < part * 32 + 32; ++c) {
            float v = sX[jr * PX + c];
            s += v; s2 += v * v;
        }
        sRed[0][part][jr] = s; sRed[1][part][jr] = s2;
    }
    __syncthreads();
    if (tid < 64) {
        float S = 0, S2 = 0;
#pragma unroll
        for (int p = 0; p < 4; ++p) { S += sRed[0][p][tid]; S2 += sRed[1][p][tid]; }
        float mean = S * (1.f / 128.f);
        float var = S2 * (1.f / 128.f) - mean * mean;
        sMV[tid] = make_float2(mean, rsqrtf(var + 1e-5f));
    }
    __syncthreads();
    {
        int row = tid & 63, c0 = (tid >> 6) * 32;
        float2 mv = sMV[row];
#pragma unroll
        for (int c = c0; c < c0 + 32; ++c) {
            float v = (sX[row * PX + c] - mv.x) * mv.y * lg[c] + lb[c];
            sA[row * PK + c] = f2bf(v);
        }
    }
    __syncthreads();
    int wave = tid >> 6, lane = tid & 63, lo = lane & 15, quad = lane >> 4;
    int msub = wave * 16;
    bf16x8 av[4];
#pragma unroll
    for (int ki = 0; ki < 4; ++ki)
        av[ki] = *(const bf16x8*)(&sA[(msub + lo) * PK + ki * 32 + quad * 8]);
    f32x4 acc[8];
#pragma unroll
    for (int nt = 0; nt < 8; ++nt) acc[nt] = (f32x4)(0.f);
#pragma unroll
    for (int nt = 0; nt < 8; ++nt)
#pragma unroll
        for (int ki = 0; ki < 4; ++ki) {
            bf16x8 b8 = *(const bf16x8*)(wzT + (nt * 16 + lo) * C + ki * 32 + quad * 8);
            acc[nt] = __builtin_amdgcn_mfma_f32_16x16x32_bf16(av[ki], b8, acc[nt], 0, 0, 0);
        }
#pragma unroll
    for (int nt = 0; nt < 8; ++nt) {
        int c = nt * 16 + lo;
        float bzv = bz[c];
#pragma unroll
        for (int r = 0; r < 4; ++r) {
            int row = msub + quad * 4 + r;
            long rr = r0 + row;
            float g = bf2f(gate[rr * C + c]);
            out[rr * C + c] = (acc[nt][r] + bzv) * g;
        }
    }
}

extern "C" void kernel_launch(void* const* d_in, const int* in_sizes, int n_in,
                              void* d_out, int out_size, void* d_ws, size_t ws_size,
                              hipStream_t stream) {
    const float* z       = (const float*)d_in[0];
    const float* mask    = (const float*)d_in[1];
    const float* w_ag    = (const float*)d_in[2];
    const float* b_ag    = (const float*)d_in[3];
    const float* w_ap    = (const float*)d_in[4];
    const float* b_ap    = (const float*)d_in[5];
    const float* w_bg    = (const float*)d_in[6];
    const float* b_bg    = (const float*)d_in[7];
    const float* w_bp    = (const float*)d_in[8];
    const float* b_bp    = (const float*)d_in[9];
    const float* w_g     = (const float*)d_in[10];
    const float* b_g     = (const float*)d_in[11];
    const float* w_z     = (const float*)d_in[12];
    const float* b_z     = (const float*)d_in[13];
    const float* ln_in_g = (const float*)d_in[14];
    const float* ln_in_b = (const float*)d_in[15];
    const float* ln_out_g= (const float*)d_in[16];
    const float* ln_out_b= (const float*)d_in[17];
    float* out = (float*)d_out;

    char* ws = (char*)d_ws;
    u16* zn   = (u16*)(ws);                          // 64 MB
    u16* a_t  = (u16*)(ws + 67108864L);              // 64 MB
    u16* b_t  = (u16*)(ws + 134217728L);             // 64 MB
    u16* gate = (u16*)(ws + 201326592L);             // 64 MB
    u16* x_t  = (u16*)(ws + 268435456L);             // 64 MB
    u16* wag_t = (u16*)(ws + 335544320L);
    u16* wap_t = wag_t + 16384;
    u16* wbg_t = wag_t + 32768;
    u16* wbp_t = wag_t + 49152;
    u16* wg_t  = wag_t + 65536;
    u16* wz_t  = wag_t + 81920;

    k_wt<<<64, 256, 0, stream>>>(w_ag, wag_t);
    k_wt<<<64, 256, 0, stream>>>(w_ap, wap_t);
    k_wt<<<64, 256, 0, stream>>>(w_bg, wbg_t);
    k_wt<<<64, 256, 0, stream>>>(w_bp, wbp_t);
    k_wt<<<64, 256, 0, stream>>>(w_g, wg_t);
    k_wt<<<64, 256, 0, stream>>>(w_z, wz_t);

    k_ln_in<<<NN / 4, 256, 0, stream>>>(z, ln_in_g, ln_in_b, zn);

    k_proj_gated<<<NN / 64, 256, 0, stream>>>(zn, mask, wag_t, b_ag, wap_t, b_ap, a_t);
    k_proj_gated<<<NN / 64, 256, 0, stream>>>(zn, mask, wbg_t, b_bg, wbp_t, b_bp, b_t);
    k_proj_gate<<<NN / 64, 256, 0, stream>>>(zn, wg_t, b_g, gate);

    k_tri<<<dim3(16, 128), 256, 0, stream>>>(a_t, b_t, x_t);

    k_out<<<NN / 64, 256, 0, stream>>>(x_t, gate, wz_t, b_z, ln_out_g, ln_out_b, out);
}

// Round 2
// 582.478 us; speedup vs baseline: 1.3417x; 1.3417x over previous
//
#include <hip/hip_runtime.h>
#include <hip/hip_bf16.h>
#include <math.h>

// TriangleMultiplicativeUpdate (outgoing), B=1 N=512 C_Z=C_H=128, fp32 in/out.
// R1: fused LN(z)+5 projections into one kernel (weights hoisted to VGPRs,
//     nt split across waves -> no serialized global-load chain).
// Pipeline: K0 weight transpose ; K_proj_fused -> a_t[c][r], b_t[c][r], gate[r][c] ;
// K3 per-channel 512^3 BT-GEMM -> x_t[c][i][j] bf16 ; K4 LN+w_z+gate -> out fp32.

#define N 512
#define C 128
#define NN (N*N)
#define PK 136   // padded LDS stride for K=128 bf16 tiles (2-way bank alias = free)
#define PT 40    // padded LDS stride for K=32 bf16 tiles
#define PX 137   // padded LDS stride for fp32 x-tile transpose

typedef __attribute__((ext_vector_type(8))) short bf16x8;
typedef __attribute__((ext_vector_type(4))) float f32x4;
typedef unsigned short u16;
typedef unsigned int u32;

__device__ __forceinline__ u16 f2bf(float f) {
    u32 u = __builtin_bit_cast(u32, f);
    u = (u + 0x7fffu + ((u >> 16) & 1u)) >> 16;
    return (u16)u;
}
__device__ __forceinline__ float bf2f(u16 h) {
    return __builtin_bit_cast(float, ((u32)h) << 16);
}
__device__ __forceinline__ float sigmoidf(float x) {
    return 1.f / (1.f + __expf(-x));
}

// ---------------- K0: all 6 weights fp32 [in][out] -> bf16 transposed -------
__global__ __launch_bounds__(256) void k_wt_all(
    const float* __restrict__ w0, const float* __restrict__ w1,
    const float* __restrict__ w2, const float* __restrict__ w3,
    const float* __restrict__ w4, const float* __restrict__ w5,
    u16* __restrict__ o0, u16* __restrict__ o1, u16* __restrict__ o2,
    u16* __restrict__ o3, u16* __restrict__ o4, u16* __restrict__ o5) {
    int sel = blockIdx.x >> 6;
    int idx = (blockIdx.x & 63) * 256 + threadIdx.x;
    const float* w = sel == 0 ? w0 : sel == 1 ? w1 : sel == 2 ? w2
                   : sel == 3 ? w3 : sel == 4 ? w4 : w5;
    u16* o = sel == 0 ? o0 : sel == 1 ? o1 : sel == 2 ? o2
           : sel == 3 ? o3 : sel == 4 ? o4 : o5;
    int co = idx >> 7, k = idx & 127;
    o[idx] = f2bf(w[k * C + co]);
}

// ---------------- fused: LN(z) + a/b/gate projections -----------------------
// block = 256 threads, 64 rows. Wave w owns output cols [w*32, w*32+32).
__global__ __launch_bounds__(256) void k_proj_fused(
    const float* __restrict__ z, const float* __restrict__ mask,
    const float* __restrict__ lg, const float* __restrict__ lb,
    const u16* __restrict__ wag, const float* __restrict__ bag,
    const u16* __restrict__ wap, const float* __restrict__ bap,
    const u16* __restrict__ wbg, const float* __restrict__ bbg,
    const u16* __restrict__ wbp, const float* __restrict__ bbp,
    const u16* __restrict__ wgg, const float* __restrict__ bgg,
    u16* __restrict__ aT, u16* __restrict__ bT, u16* __restrict__ gate) {
    __shared__ u16 sA[64 * PK];
    __shared__ u16 sT[128 * 72];
    long r0 = (long)blockIdx.x * 64;
    int tid = threadIdx.x, wave = tid >> 6, lane = tid & 63;
    int lo = lane & 15, quad = lane >> 4;

    // --- LN(z) -> sA (bf16, MFMA A layout) ---
    {
        int c = lane * 2;
        float g0 = lg[c], g1 = lg[c + 1], b0 = lb[c], b1 = lb[c + 1];
        for (int rr = 0; rr < 16; ++rr) {
            int row = wave * 16 + rr;
            float2 xv = *(const float2*)(z + (r0 + row) * C + c);
            float s = xv.x + xv.y, s2 = xv.x * xv.x + xv.y * xv.y;
#pragma unroll
            for (int off = 32; off; off >>= 1) {
                s += __shfl_xor(s, off);
                s2 += __shfl_xor(s2, off);
            }
            float mean = s * (1.f / 128.f);
            float var = s2 * (1.f / 128.f) - mean * mean;
            float rs = rsqrtf(var + 1e-5f);
            float y0 = (xv.x - mean) * rs * g0 + b0;
            float y1 = (xv.y - mean) * rs * g1 + b1;
            *(u32*)(&sA[row * PK + c]) = (u32)f2bf(y0) | ((u32)f2bf(y1) << 16);
        }
    }
    __syncthreads();

    int c0 = wave * 32;
    float msk[4][4];
#pragma unroll
    for (int mi = 0; mi < 4; ++mi)
#pragma unroll
        for (int r = 0; r < 4; ++r)
            msk[mi][r] = mask[r0 + mi * 16 + quad * 4 + r];

    // --- gated pair stage: outT[c][r] = mask*sigmoid(zn@wG+bG)*(zn@wP+bP) ---
    auto pair_stage = [&](const u16* __restrict__ wG, const float* __restrict__ bG,
                          const u16* __restrict__ wP, const float* __restrict__ bP,
                          u16* __restrict__ outT) {
        bf16x8 fG[2][4], fP[2][4];
#pragma unroll
        for (int nt = 0; nt < 2; ++nt)
#pragma unroll
            for (int ki = 0; ki < 4; ++ki) {
                fG[nt][ki] = *(const bf16x8*)(wG + (c0 + nt * 16 + lo) * C + ki * 32 + quad * 8);
                fP[nt][ki] = *(const bf16x8*)(wP + (c0 + nt * 16 + lo) * C + ki * 32 + quad * 8);
            }
        f32x4 aG[4][2], aP[4][2];
#pragma unroll
        for (int mi = 0; mi < 4; ++mi)
#pragma unroll
            for (int nt = 0; nt < 2; ++nt) { aG[mi][nt] = (f32x4)(0.f); aP[mi][nt] = (f32x4)(0.f); }
#pragma unroll
        for (int mi = 0; mi < 4; ++mi)
#pragma unroll
            for (int ki = 0; ki < 4; ++ki) {
                bf16x8 av = *(const bf16x8*)(&sA[(mi * 16 + lo) * PK + ki * 32 + quad * 8]);
#pragma unroll
                for (int nt = 0; nt < 2; ++nt) {
                    aG[mi][nt] = __builtin_amdgcn_mfma_f32_16x16x32_bf16(av, fG[nt][ki], aG[mi][nt], 0, 0, 0);
                    aP[mi][nt] = __builtin_amdgcn_mfma_f32_16x16x32_bf16(av, fP[nt][ki], aP[mi][nt], 0, 0, 0);
                }
            }
#pragma unroll
        for (int nt = 0; nt < 2; ++nt) {
            int c = c0 + nt * 16 + lo;
            float bGv = bG[c], bPv = bP[c];
#pragma unroll
            for (int mi = 0; mi < 4; ++mi)
#pragma unroll
                for (int r = 0; r < 4; ++r) {
                    int row = mi * 16 + quad * 4 + r;
                    float val = msk[mi][r] * sigmoidf(aG[mi][nt][r] + bGv) * (aP[mi][nt][r] + bPv);
                    sT[c * 72 + row] = f2bf(val);
                }
        }
        __syncthreads();
#pragma unroll
        for (int p = 0; p < 4; ++p) {
            int linear = p * 2048 + tid * 8;
            int cc = linear >> 6, row = linear & 63;
            *(uint4*)(outT + (long)cc * NN + r0 + row) = *(const uint4*)(&sT[cc * 72 + row]);
        }
        __syncthreads();
    };
    pair_stage(wag, bag, wap, bap, aT);
    pair_stage(wbg, bbg, wbp, bbp, bT);

    // --- gate stage: gate[r][c] = sigmoid(zn@w_g + b_g) ---
    {
        bf16x8 fG[2][4];
#pragma unroll
        for (int nt = 0; nt < 2; ++nt)
#pragma unroll
            for (int ki = 0; ki < 4; ++ki)
                fG[nt][ki] = *(const bf16x8*)(wgg + (c0 + nt * 16 + lo) * C + ki * 32 + quad * 8);
        f32x4 aG[4][2];
#pragma unroll
        for (int mi = 0; mi < 4; ++mi)
#pragma unroll
            for (int nt = 0; nt < 2; ++nt) aG[mi][nt] = (f32x4)(0.f);
#pragma unroll
        for (int mi = 0; mi < 4; ++mi)
#pragma unroll
            for (int ki = 0; ki < 4; ++ki) {
                bf16x8 av = *(const bf16x8*)(&sA[(mi * 16 + lo) * PK + ki * 32 + quad * 8]);
#pragma unroll
                for (int nt = 0; nt < 2; ++nt)
                    aG[mi][nt] = __builtin_amdgcn_mfma_f32_16x16x32_bf16(av, fG[nt][ki], aG[mi][nt], 0, 0, 0);
            }
        __syncthreads();   // all waves done reading sA before overwrite
#pragma unroll
        for (int nt = 0; nt < 2; ++nt) {
            int c = c0 + nt * 16 + lo;
            float bv = bgg[c];
#pragma unroll
            for (int mi = 0; mi < 4; ++mi)
#pragma unroll
                for (int r = 0; r < 4; ++r) {
                    int row = mi * 16 + quad * 4 + r;
                    sA[row * PK + c] = f2bf(sigmoidf(aG[mi][nt][r] + bv));
                }
        }
        __syncthreads();
#pragma unroll
        for (int p = 0; p < 4; ++p) {
            int linear = p * 2048 + tid * 8;
            int row = linear >> 7, k = linear & 127;
            *(uint4*)(gate + (r0 + row) * C + k) = *(const uint4*)(&sA[row * PK + k]);
        }
    }
}

// ---------------- K3: per-channel 512x512x512 BT-GEMM -----------------------
// x_t[c][i][j] = sum_k a_t[c][i][k] * b_t[c][j][k]
__global__ __launch_bounds__(256) void k_tri(const u16* __restrict__ aT,
                                             const u16* __restrict__ bT,
                                             u16* __restrict__ xT) {
    __shared__ u16 sA[128 * PT];
    __shared__ u16 sB[128 * PT];
    int c = blockIdx.y;
    int i0 = (blockIdx.x >> 2) * 128, j0 = (blockIdx.x & 3) * 128;
    const u16* aBase = aT + (long)c * NN + (long)i0 * N;
    const u16* bBase = bT + (long)c * NN + (long)j0 * N;
    int tid = threadIdx.x;
    int wave = tid >> 6, lane = tid & 63, lo = lane & 15, quad = lane >> 4;
    int mq = (wave >> 1) * 64, nq = (wave & 1) * 64;
    f32x4 acc[4][4];
#pragma unroll
    for (int mi = 0; mi < 4; ++mi)
#pragma unroll
        for (int ni = 0; ni < 4; ++ni) acc[mi][ni] = (f32x4)(0.f);
    for (int kk = 0; kk < N; kk += 32) {
        __syncthreads();
#pragma unroll
        for (int p = 0; p < 2; ++p) {
            int linear = p * 2048 + tid * 8;
            int row = linear >> 5, k = linear & 31;
            *(uint4*)(&sA[row * PT + k]) = *(const uint4*)(aBase + row * N + kk + k);
            *(uint4*)(&sB[row * PT + k]) = *(const uint4*)(bBase + row * N + kk + k);
        }
        __syncthreads();
        bf16x8 af[4], bfr[4];
#pragma unroll
        for (int mi = 0; mi < 4; ++mi)
            af[mi] = *(const bf16x8*)(&sA[(mq + mi * 16 + lo) * PT + quad * 8]);
#pragma unroll
        for (int ni = 0; ni < 4; ++ni)
            bfr[ni] = *(const bf16x8*)(&sB[(nq + ni * 16 + lo) * PT + quad * 8]);
#pragma unroll
        for (int mi = 0; mi < 4; ++mi)
#pragma unroll
            for (int ni = 0; ni < 4; ++ni)
                acc[mi][ni] = __builtin_amdgcn_mfma_f32_16x16x32_bf16(af[mi], bfr[ni], acc[mi][ni], 0, 0, 0);
    }
    u16* outBase = xT + (long)c * NN;
#pragma unroll
    for (int mi = 0; mi < 4; ++mi)
#pragma unroll
        for (int ni = 0; ni < 4; ++ni)
#pragma unroll
            for (int r = 0; r < 4; ++r) {
                int gi = i0 + mq + mi * 16 + quad * 4 + r;
                int gj = j0 + nq + ni * 16 + lo;
                outBase[(long)gi * N + gj] = f2bf(acc[mi][ni][r]);
            }
}

// ---------------- K4: LN(x) @ w_z + b_z, * gate -> out fp32 -----------------
__global__ __launch_bounds__(256) void k_out(
    const u16* __restrict__ xT, const u16* __restrict__ gate,
    const u16* __restrict__ wzT, const float* __restrict__ bz,
    const float* __restrict__ lg, const float* __restrict__ lb,
    float* __restrict__ out) {
    __shared__ float sX[64 * PX];
    __shared__ u16 sA[64 * PK];
    __shared__ float sRed[2][4][64];
    __shared__ float2 sMV[64];
    long r0 = (long)blockIdx.x * 64;
    int tid = threadIdx.x;
#pragma unroll
    for (int p = 0; p < 4; ++p) {
        int linear = p * 2048 + tid * 8;
        int cc = linear >> 6, jr = linear & 63;
        uint4 v = *(const uint4*)(xT + (long)cc * NN + r0 + jr);
        u16* u = (u16*)&v;
#pragma unroll
        for (int e = 0; e < 8; ++e) sX[(jr + e) * PX + cc] = bf2f(u[e]);
    }
    __syncthreads();
    {
        int jr = tid & 63, part = tid >> 6;
        float s = 0, s2 = 0;
#pragma unroll
        for (int c = part * 32; c < part * 32 + 32; ++c) {
            float v = sX[jr * PX + c];
            s += v; s2 += v * v;
        }
        sRed[0][part][jr] = s; sRed[1][part][jr] = s2;
    }
    __syncthreads();
    if (tid < 64) {
        float S = 0, S2 = 0;
#pragma unroll
        for (int p = 0; p < 4; ++p) { S += sRed[0][p][tid]; S2 += sRed[1][p][tid]; }
        float mean = S * (1.f / 128.f);
        float var = S2 * (1.f / 128.f) - mean * mean;
        sMV[tid] = make_float2(mean, rsqrtf(var + 1e-5f));
    }
    __syncthreads();
    {
        int row = tid & 63, c0 = (tid >> 6) * 32;
        float2 mv = sMV[row];
#pragma unroll
        for (int c = c0; c < c0 + 32; ++c) {
            float v = (sX[row * PX + c] - mv.x) * mv.y * lg[c] + lb[c];
            sA[row * PK + c] = f2bf(v);
        }
    }
    __syncthreads();
    int wave = tid >> 6, lane = tid & 63, lo = lane & 15, quad = lane >> 4;
    int msub = wave * 16;
    bf16x8 av[4];
#pragma unroll
    for (int ki = 0; ki < 4; ++ki)
        av[ki] = *(const bf16x8*)(&sA[(msub + lo) * PK + ki * 32 + quad * 8]);
    f32x4 acc[8];
#pragma unroll
    for (int nt = 0; nt < 8; ++nt) acc[nt] = (f32x4)(0.f);
#pragma unroll
    for (int nt = 0; nt < 8; ++nt)
#pragma unroll
        for (int ki = 0; ki < 4; ++ki) {
            bf16x8 b8 = *(const bf16x8*)(wzT + (nt * 16 + lo) * C + ki * 32 + quad * 8);
            acc[nt] = __builtin_amdgcn_mfma_f32_16x16x32_bf16(av[ki], b8, acc[nt], 0, 0, 0);
        }
#pragma unroll
    for (int nt = 0; nt < 8; ++nt) {
        int c = nt * 16 + lo;
        float bzv = bz[c];
#pragma unroll
        for (int r = 0; r < 4; ++r) {
            int row = msub + quad * 4 + r;
            long rr = r0 + row;
            float g = bf2f(gate[rr * C + c]);
            out[rr * C + c] = (acc[nt][r] + bzv) * g;
        }
    }
}

extern "C" void kernel_launch(void* const* d_in, const int* in_sizes, int n_in,
                              void* d_out, int out_size, void* d_ws, size_t ws_size,
                              hipStream_t stream) {
    const float* z       = (const float*)d_in[0];
    const float* mask    = (const float*)d_in[1];
    const float* w_ag    = (const float*)d_in[2];
    const float* b_ag    = (const float*)d_in[3];
    const float* w_ap    = (const float*)d_in[4];
    const float* b_ap    = (const float*)d_in[5];
    const float* w_bg    = (const float*)d_in[6];
    const float* b_bg    = (const float*)d_in[7];
    const float* w_bp    = (const float*)d_in[8];
    const float* b_bp    = (const float*)d_in[9];
    const float* w_g     = (const float*)d_in[10];
    const float* b_g     = (const float*)d_in[11];
    const float* w_z     = (const float*)d_in[12];
    const float* b_z     = (const float*)d_in[13];
    const float* ln_in_g = (const float*)d_in[14];
    const float* ln_in_b = (const float*)d_in[15];
    const float* ln_out_g= (const float*)d_in[16];
    const float* ln_out_b= (const float*)d_in[17];
    float* out = (float*)d_out;

    char* ws = (char*)d_ws;
    u16* a_t  = (u16*)(ws);                          // 64 MB
    u16* b_t  = (u16*)(ws + 67108864L);              // 64 MB
    u16* gate = (u16*)(ws + 134217728L);             // 64 MB
    u16* x_t  = (u16*)(ws + 201326592L);             // 64 MB
    u16* wag_t = (u16*)(ws + 268435456L);
    u16* wap_t = wag_t + 16384;
    u16* wbg_t = wag_t + 32768;
    u16* wbp_t = wag_t + 49152;
    u16* wg_t  = wag_t + 65536;
    u16* wz_t  = wag_t + 81920;

    k_wt_all<<<384, 256, 0, stream>>>(w_ag, w_ap, w_bg, w_bp, w_g, w_z,
                                      wag_t, wap_t, wbg_t, wbp_t, wg_t, wz_t);

    k_proj_fused<<<NN / 64, 256, 0, stream>>>(
        z, mask, ln_in_g, ln_in_b,
        wag_t, b_ag, wap_t, b_ap, wbg_t, b_bg, wbp_t, b_bp, wg_t, b_g,
        a_t, b_t, gate);

    k_tri<<<dim3(16, 128), 256, 0, stream>>>(a_t, b_t, x_t);

    k_out<<<NN / 64, 256, 0, stream>>>(x_t, gate, wz_t, b_z, ln_out_g, ln_out_b, out);
}